// Round 1
// baseline (432.867 us; speedup 1.0000x reference)
//
#include <hip/hip_runtime.h>
#include <stdint.h>
#include <stddef.h>

#define NHEAD 16
#define DMODEL 1024
#define SS 2048
#define BB 2
#define NEGV -1e10f

typedef __attribute__((ext_vector_type(8))) short bf16x8;
typedef __attribute__((ext_vector_type(4))) float f32x4;
typedef __attribute__((ext_vector_type(4))) float floatv4;
typedef __attribute__((ext_vector_type(4))) unsigned short ushortv4;

#define MFMA16(A, B, C) __builtin_amdgcn_mfma_f32_16x16x32_bf16(A, B, C, 0, 0, 0)

__device__ __forceinline__ unsigned short f2bf(float f) {
    union { float f; unsigned u; } x;
    x.f = f;
    unsigned r = x.u + 0x7FFFu + ((x.u >> 16) & 1u);  // RNE
    return (unsigned short)(r >> 16);
}

// ---------------- convert fp32 -> bf16 (vectorized) ----------------
__global__ __launch_bounds__(256) void cvt_bf16(const float* __restrict__ in,
                                                unsigned short* __restrict__ out, int n4) {
    int i = blockIdx.x * 256 + threadIdx.x;
    if (i >= n4) return;
    floatv4 v = ((const floatv4*)in)[i];
    ushortv4 o;
    o.x = f2bf(v.x); o.y = f2bf(v.y); o.z = f2bf(v.z); o.w = f2bf(v.w);
    ((ushortv4*)out)[i] = o;
}

// ---------------- weight transpose + convert: W[k][n] f32 -> Wt[n][k] bf16 ----------------
__global__ __launch_bounds__(256) void wtrans(const float* __restrict__ W,
                                              unsigned short* __restrict__ Wt) {
    __shared__ float tile[32][33];
    int tx = threadIdx.x & 31, ty = threadIdx.x >> 5;   // ty 0..7
    int nb = blockIdx.x * 32, kb = blockIdx.y * 32;
#pragma unroll
    for (int i = 0; i < 4; i++)
        tile[ty + i * 8][tx] = W[(size_t)(kb + ty + i * 8) * DMODEL + nb + tx];
    __syncthreads();
#pragma unroll
    for (int i = 0; i < 4; i++)
        Wt[(size_t)(nb + ty + i * 8) * DMODEL + kb + tx] = f2bf(tile[tx][ty + i * 8]);
}

// ---------------- GEMM core: 128x128 tile, BK=64, 4 waves, swizzled LDS ----------------
// LDS tile layout: [128 rows][64 bf16], row stride 128B. XOR swizzle: u16 index
// column ^= (row&7)<<3 (16B-granule permute) to kill ds_read_b128 bank conflicts.
// Staging via global_load_lds (linear LDS dest, pre-swizzled global source).
__device__ __forceinline__ void stage_tile_sw(const unsigned short* __restrict__ src, int ld,
                                              unsigned short* lds) {
    int t = threadIdx.x;
#pragma unroll
    for (int i = 0; i < 4; i++) {
        int pos = i * 256 + t;            // 16B granule index
        int row = pos >> 3;
        int g = pos & 7;
        int kcol = (g ^ (row & 7)) * 8;   // inverse-swizzled source column
        __builtin_amdgcn_global_load_lds(
            (__attribute__((address_space(1))) void*)(src + row * ld + kcol),
            (__attribute__((address_space(3))) void*)(lds + pos * 8), 16, 0, 0);
    }
}

__device__ __forceinline__ bf16x8 frag_ld(const unsigned short* lds, int row, int koff) {
    int idx = row * 64 + (koff ^ ((row & 7) << 3));
    return *(const bf16x8*)(lds + idx);
}

__device__ __forceinline__ void gemm_core(const unsigned short* __restrict__ A,
                                          const unsigned short* __restrict__ Bt,
                                          int mbase, int nbase,
                                          unsigned short* As, unsigned short* Bs,
                                          f32x4 acc[4][4]) {
    int tid = threadIdx.x;
    int w = tid >> 6, lane = tid & 63, lg = lane >> 4, li = lane & 15;
    int wm = w >> 1, wn = w & 1;
#pragma unroll
    for (int mi = 0; mi < 4; mi++)
#pragma unroll
        for (int ni = 0; ni < 4; ni++) acc[mi][ni] = f32x4{0.f, 0.f, 0.f, 0.f};

    for (int ks = 0; ks < DMODEL / 64; ks++) {
        __syncthreads();  // protect previous tile reads
        stage_tile_sw(A + (size_t)mbase * DMODEL + ks * 64, DMODEL, As);
        stage_tile_sw(Bt + (size_t)nbase * DMODEL + ks * 64, DMODEL, Bs);
        __syncthreads();  // staged (vmcnt drained by barrier)
        bf16x8 af[2][4], bfr[2][4];
#pragma unroll
        for (int kc = 0; kc < 2; kc++) {
#pragma unroll
            for (int mi = 0; mi < 4; mi++)
                af[kc][mi] = frag_ld(As, wm * 64 + mi * 16 + li, kc * 32 + lg * 8);
#pragma unroll
            for (int ni = 0; ni < 4; ni++)
                bfr[kc][ni] = frag_ld(Bs, wn * 64 + ni * 16 + li, kc * 32 + lg * 8);
        }
#pragma unroll
        for (int kc = 0; kc < 2; kc++)
#pragma unroll
            for (int mi = 0; mi < 4; mi++)
#pragma unroll
                for (int ni = 0; ni < 4; ni++)
                    acc[mi][ni] = MFMA16(af[kc][mi], bfr[kc][ni], acc[mi][ni]);
    }
}

// ---------------- fused QKV projection ----------------
// grid (24, 32): x = seg*8 + ntile, y = mtile. Epilogue scatters to [B,H,S,64] bf16.
__global__ __launch_bounds__(256) void gemm_qkv(
    const unsigned short* __restrict__ qb, const unsigned short* __restrict__ kbuf,
    const unsigned short* __restrict__ vb,
    const unsigned short* __restrict__ Wqt, const unsigned short* __restrict__ Wkt,
    const unsigned short* __restrict__ Wvt,
    unsigned short* __restrict__ Qp, unsigned short* __restrict__ Kp,
    unsigned short* __restrict__ Vp) {
    __shared__ unsigned short As[128 * 64], Bs[128 * 64];
    int nt = blockIdx.x;
    int seg = nt >> 3;
    int nbase = (nt & 7) * 128;
    int mbase = blockIdx.y * 128;
    const unsigned short* A = seg == 0 ? qb : (seg == 1 ? kbuf : vb);
    const unsigned short* Bt = seg == 0 ? Wqt : (seg == 1 ? Wkt : Wvt);
    unsigned short* Out = seg == 0 ? Qp : (seg == 1 ? Kp : Vp);

    f32x4 acc[4][4];
    gemm_core(A, Bt, mbase, nbase, As, Bs, acc);

    int tid = threadIdx.x, w = tid >> 6, lane = tid & 63, lg = lane >> 4, li = lane & 15;
    int wm = w >> 1, wn = w & 1;
#pragma unroll
    for (int mi = 0; mi < 4; mi++)
#pragma unroll
        for (int ni = 0; ni < 4; ni++) {
            int n = nbase + wn * 64 + ni * 16 + li;
            int h = n >> 6, d = n & 63;
#pragma unroll
            for (int r = 0; r < 4; r++) {
                int m = mbase + wm * 64 + mi * 16 + lg * 4 + r;
                int b = m >> 11, sI = m & 2047;
                Out[(size_t)((b * NHEAD + h) * SS + sI) * 64 + d] = f2bf(acc[mi][ni][r]);
            }
        }
}

// ---------------- output projection + bias + residual ----------------
__global__ __launch_bounds__(256) void gemm_out(
    const unsigned short* __restrict__ Ob, const unsigned short* __restrict__ Wot,
    const float* __restrict__ bo, const float* __restrict__ qres, float* __restrict__ Y) {
    __shared__ unsigned short As[128 * 64], Bs[128 * 64];
    int nbase = blockIdx.x * 128;
    int mbase = blockIdx.y * 128;

    f32x4 acc[4][4];
    gemm_core(Ob, Wot, mbase, nbase, As, Bs, acc);

    int tid = threadIdx.x, w = tid >> 6, lane = tid & 63, lg = lane >> 4, li = lane & 15;
    int wm = w >> 1, wn = w & 1;
#pragma unroll
    for (int mi = 0; mi < 4; mi++)
#pragma unroll
        for (int ni = 0; ni < 4; ni++) {
            int n = nbase + wn * 64 + ni * 16 + li;
            float bov = bo[n];
#pragma unroll
            for (int r = 0; r < 4; r++) {
                int m = mbase + wm * 64 + mi * 16 + lg * 4 + r;
                size_t idx = (size_t)m * DMODEL + n;
                Y[idx] = acc[mi][ni][r] + bov + qres[idx];
            }
        }
}

// ---------------- fused attention ----------------
// grid (16, 32): x = q-block (128 rows), y = bh. Block = 4 waves, 32 q-rows/wave.
// Pass A: online row-max/row-sum over K tiles (KB=128), K read direct from global (L2-resident).
// Pass B: recompute scores, write normalized P (fp32) to d_out, P->bf16 via swizzled
// per-wave LDS transpose, accumulate P·V with V transposed into swizzled shared LDS.
__device__ __forceinline__ void compute_scores(const unsigned short* __restrict__ Kb,
                                               const int* __restrict__ mb,
                                               const bf16x8 (&qa)[2][2],
                                               int k0, int lg, int li, float s[2][8][4]) {
#pragma unroll
    for (int fk = 0; fk < 8; fk++) {
        int kcol = k0 + fk * 16 + li;
        bf16x8 kf0 = *(const bf16x8*)(Kb + (size_t)kcol * 64 + lg * 8);
        bf16x8 kf1 = *(const bf16x8*)(Kb + (size_t)kcol * 64 + 32 + lg * 8);
        int mv = mb[kcol];
#pragma unroll
        for (int fq = 0; fq < 2; fq++) {
            f32x4 sc = f32x4{0.f, 0.f, 0.f, 0.f};
            sc = MFMA16(qa[fq][0], kf0, sc);
            sc = MFMA16(qa[fq][1], kf1, sc);
#pragma unroll
            for (int r = 0; r < 4; r++)
                s[fq][fk][r] = (mv == 0) ? NEGV : sc[r] * 0.03125f;  // /sqrt(d_model)=32
        }
    }
}

__global__ __launch_bounds__(256) void attn_fused(
    const unsigned short* __restrict__ Qp, const unsigned short* __restrict__ Kp,
    const unsigned short* __restrict__ Vp, const int* __restrict__ mask,
    float* __restrict__ attn_out, unsigned short* __restrict__ Ob) {
    __shared__ unsigned short Plds[4 * 32 * 128];  // per-wave 32x128 bf16, swizzled
    __shared__ unsigned short Vt[64 * 128];        // V^T tile [d][s], swizzled, shared

    int bh = blockIdx.y;
    int b = bh >> 4;
    int q0 = blockIdx.x * 128;
    int tid = threadIdx.x, w = tid >> 6, lane = tid & 63, lg = lane >> 4, li = lane & 15;
    const unsigned short* Qb = Qp + (size_t)bh * SS * 64;
    const unsigned short* Kb = Kp + (size_t)bh * SS * 64;
    const unsigned short* Vb = Vp + (size_t)bh * SS * 64;
    const int* mb = mask + b * SS;
    int qw = q0 + w * 32;

    // Q fragments in registers, reused across all K tiles
    bf16x8 qa[2][2];
#pragma unroll
    for (int fq = 0; fq < 2; fq++)
#pragma unroll
        for (int dc = 0; dc < 2; dc++) {
            int q = qw + fq * 16 + li;
            qa[fq][dc] = *(const bf16x8*)(Qb + (size_t)q * 64 + dc * 32 + lg * 8);
        }

    float mrun[8], lrun[8];
#pragma unroll
    for (int i = 0; i < 8; i++) { mrun[i] = -3.0e38f; lrun[i] = 0.f; }

    // ---- pass A: online max/sum ----
    for (int kt = 0; kt < SS / 128; kt++) {
        float s[2][8][4];
        compute_scores(Kb, mb, qa, kt * 128, lg, li, s);
#pragma unroll
        for (int fq = 0; fq < 2; fq++)
#pragma unroll
            for (int r = 0; r < 4; r++) {
                int i = fq * 4 + r;
                float tm = s[fq][0][r];
#pragma unroll
                for (int fk = 1; fk < 8; fk++) tm = fmaxf(tm, s[fq][fk][r]);
#pragma unroll
                for (int msk = 1; msk < 16; msk <<= 1) tm = fmaxf(tm, __shfl_xor(tm, msk));
                float mnew = fmaxf(mrun[i], tm);
                float corr = __expf(mrun[i] - mnew);
                float ps = 0.f;
#pragma unroll
                for (int fk = 0; fk < 8; fk++) ps += __expf(s[fq][fk][r] - mnew);
#pragma unroll
                for (int msk = 1; msk < 16; msk <<= 1) ps += __shfl_xor(ps, msk);
                lrun[i] = lrun[i] * corr + ps;
                mrun[i] = mnew;
            }
    }
    float linv[8];
#pragma unroll
    for (int i = 0; i < 8; i++) linv[i] = 1.0f / lrun[i];

    // ---- pass B: P write + PV ----
    f32x4 oacc[2][4];
#pragma unroll
    for (int fq = 0; fq < 2; fq++)
#pragma unroll
        for (int gd = 0; gd < 4; gd++) oacc[fq][gd] = f32x4{0.f, 0.f, 0.f, 0.f};

    unsigned short* Pw = Plds + w * (32 * 128);

    for (int kt = 0; kt < SS / 128; kt++) {
        int k0 = kt * 128;
        float s[2][8][4];
        compute_scores(Kb, mb, qa, k0, lg, li, s);
#pragma unroll
        for (int fq = 0; fq < 2; fq++)
#pragma unroll
            for (int fk = 0; fk < 8; fk++)
#pragma unroll
                for (int r = 0; r < 4; r++) {
                    int i = fq * 4 + r;
                    float p = __expf(s[fq][fk][r] - mrun[i]) * linv[i];
                    int qrow = qw + fq * 16 + lg * 4 + r;
                    attn_out[(size_t)(bh * SS + qrow) * SS + (k0 + fk * 16 + li)] = p;
                    int qr = fq * 16 + lg * 4 + r;
                    *(unsigned short*)((char*)Pw +
                        (qr * 256 + ((fk * 32 + li * 2) ^ ((qr & 7) << 4)))) = f2bf(p);
                }

        // stage V^T tile (cooperative)
        __syncthreads();
        {
            int sl = tid & 127;
            int d0 = (tid >> 7) * 32;
#pragma unroll
            for (int c = 0; c < 4; c++) {
                bf16x8 vv = *(const bf16x8*)(Vb + (size_t)(k0 + sl) * 64 + d0 + c * 8);
#pragma unroll
                for (int j = 0; j < 8; j++) {
                    int d = d0 + c * 8 + j;
                    *(unsigned short*)((char*)Vt + ((d * 256 + sl * 2) ^ ((d & 7) << 4))) =
                        (unsigned short)vv[j];
                }
            }
        }
        __syncthreads();

        // PV MFMAs
#pragma unroll
        for (int kc = 0; kc < 4; kc++) {
            int koff = kc * 64 + lg * 16;
            bf16x8 pa[2];
#pragma unroll
            for (int fq = 0; fq < 2; fq++) {
                int qr = fq * 16 + li;
                pa[fq] = *(const bf16x8*)((const char*)Pw + (qr * 256 + (koff ^ ((qr & 7) << 4))));
            }
            bf16x8 vf[4];
#pragma unroll
            for (int gd = 0; gd < 4; gd++) {
                int d = gd * 16 + li;
                vf[gd] = *(const bf16x8*)((const char*)Vt + (d * 256 + (koff ^ ((d & 7) << 4))));
            }
#pragma unroll
            for (int fq = 0; fq < 2; fq++)
#pragma unroll
                for (int gd = 0; gd < 4; gd++)
                    oacc[fq][gd] = MFMA16(pa[fq], vf[gd], oacc[fq][gd]);
        }
    }

    // epilogue: O -> [b*S + s][h*64 + d] bf16
    int h = bh & 15;
#pragma unroll
    for (int fq = 0; fq < 2; fq++)
#pragma unroll
        for (int gd = 0; gd < 4; gd++)
#pragma unroll
            for (int r = 0; r < 4; r++) {
                int srow = qw + fq * 16 + lg * 4 + r;
                int d = gd * 16 + li;
                Ob[(size_t)(b * SS + srow) * DMODEL + h * 64 + d] = f2bf(oacc[fq][gd][r]);
            }
}

// ---------------- LayerNorm ----------------
__global__ __launch_bounds__(256) void ln_kernel(const float* __restrict__ Y,
                                                 const float* __restrict__ gamma,
                                                 const float* __restrict__ beta,
                                                 float* __restrict__ out) {
    int row = blockIdx.x;
    int t = threadIdx.x;
    floatv4 v = ((const floatv4*)(Y + (size_t)row * DMODEL))[t];
    float s1 = v.x + v.y + v.z + v.w;
    float s2 = v.x * v.x + v.y * v.y + v.z * v.z + v.w * v.w;
#pragma unroll
    for (int m = 1; m < 64; m <<= 1) { s1 += __shfl_xor(s1, m); s2 += __shfl_xor(s2, m); }
    __shared__ float red[8];
    int w = t >> 6, lane = t & 63;
    if (lane == 0) { red[w] = s1; red[4 + w] = s2; }
    __syncthreads();
    s1 = red[0] + red[1] + red[2] + red[3];
    s2 = red[4] + red[5] + red[6] + red[7];
    float mu = s1 * (1.0f / DMODEL);
    float var = s2 * (1.0f / DMODEL) - mu * mu;
    float rstd = rsqrtf(var + 1e-5f);
    floatv4 g = ((const floatv4*)gamma)[t];
    floatv4 bb = ((const floatv4*)beta)[t];
    floatv4 o;
    o.x = (v.x - mu) * rstd * g.x + bb.x;
    o.y = (v.y - mu) * rstd * g.y + bb.y;
    o.z = (v.z - mu) * rstd * g.z + bb.z;
    o.w = (v.w - mu) * rstd * g.w + bb.w;
    ((floatv4*)(out + (size_t)row * DMODEL))[t] = o;
}

// ---------------- launch ----------------
extern "C" void kernel_launch(void* const* d_in, const int* in_sizes, int n_in,
                              void* d_out, int out_size, void* d_ws, size_t ws_size,
                              hipStream_t stream) {
    const float* q = (const float*)d_in[0];
    const float* k = (const float*)d_in[1];
    const float* v = (const float*)d_in[2];
    const int* mask = (const int*)d_in[3];
    const float* Wq = (const float*)d_in[4];
    const float* Wk = (const float*)d_in[5];
    const float* Wv = (const float*)d_in[6];
    const float* Wo = (const float*)d_in[7];
    const float* bo = (const float*)d_in[8];
    const float* gamma = (const float*)d_in[9];
    const float* beta = (const float*)d_in[10];

    float* out = (float*)d_out;
    float* attn = out + (size_t)BB * SS * DMODEL;

    const size_t NTOK = (size_t)BB * SS;          // 4096
    unsigned short* qb = (unsigned short*)d_ws;   // [4096][1024] bf16
    unsigned short* kb = qb + NTOK * DMODEL;
    unsigned short* vb = kb + NTOK * DMODEL;
    unsigned short* Wqt = vb + NTOK * DMODEL;     // [1024][1024] bf16 (transposed)
    unsigned short* Wkt = Wqt + (size_t)DMODEL * DMODEL;
    unsigned short* Wvt = Wkt + (size_t)DMODEL * DMODEL;
    unsigned short* Wot = Wvt + (size_t)DMODEL * DMODEL;
    unsigned short* Qp = Wot + (size_t)DMODEL * DMODEL;  // [B,H,S,64] bf16
    unsigned short* Kp = Qp + NTOK * DMODEL;
    unsigned short* Vp = Kp + NTOK * DMODEL;
    unsigned short* Ob = Vp + NTOK * DMODEL;      // [4096][1024] bf16
    float* Y = (float*)qb;                        // reuse qb+kb region (16 MB) post-attention

    const int n4 = (int)(NTOK * DMODEL / 4);
    cvt_bf16<<<n4 / 256, 256, 0, stream>>>(q, qb, n4);
    cvt_bf16<<<n4 / 256, 256, 0, stream>>>(k, kb, n4);
    cvt_bf16<<<n4 / 256, 256, 0, stream>>>(v, vb, n4);

    dim3 tg(32, 32);
    wtrans<<<tg, 256, 0, stream>>>(Wq, Wqt);
    wtrans<<<tg, 256, 0, stream>>>(Wk, Wkt);
    wtrans<<<tg, 256, 0, stream>>>(Wv, Wvt);
    wtrans<<<tg, 256, 0, stream>>>(Wo, Wot);

    gemm_qkv<<<dim3(24, 32), 256, 0, stream>>>(qb, kb, vb, Wqt, Wkt, Wvt, Qp, Kp, Vp);

    attn_fused<<<dim3(16, 32), 256, 0, stream>>>(Qp, Kp, Vp, mask, attn, Ob);

    gemm_out<<<dim3(8, 32), 256, 0, stream>>>(Ob, Wot, bo, q, Y);

    ln_kernel<<<(int)NTOK, 256, 0, stream>>>(Y, gamma, beta, out);
}

// Round 2
// 381.839 us; speedup vs baseline: 1.1336x; 1.1336x over previous
//
#include <hip/hip_runtime.h>
#include <stdint.h>
#include <stddef.h>

#define NHEAD 16
#define DMODEL 1024
#define SS 2048
#define BB 2
#define NEGV -1e10f

typedef __attribute__((ext_vector_type(8))) short bf16x8;
typedef __attribute__((ext_vector_type(4))) float f32x4;
typedef __attribute__((ext_vector_type(4))) float floatv4;
typedef __attribute__((ext_vector_type(4))) unsigned short ushortv4;
typedef __attribute__((ext_vector_type(4))) int intv4;

#define MFMA16(A, B, C) __builtin_amdgcn_mfma_f32_16x16x32_bf16(A, B, C, 0, 0, 0)

__device__ __forceinline__ unsigned short f2bf(float f) {
    union { float f; unsigned u; } x;
    x.f = f;
    unsigned r = x.u + 0x7FFFu + ((x.u >> 16) & 1u);  // RNE
    return (unsigned short)(r >> 16);
}

// ---------------- convert fp32 -> bf16 (q,k,v merged) ----------------
__global__ __launch_bounds__(256) void cvt3(const float* __restrict__ q,
                                            const float* __restrict__ k,
                                            const float* __restrict__ v,
                                            unsigned short* __restrict__ qb,
                                            unsigned short* __restrict__ kb,
                                            unsigned short* __restrict__ vb, int n4) {
    int i = blockIdx.x * 256 + threadIdx.x;
    if (i >= n4) return;
    const float* src = blockIdx.y == 0 ? q : (blockIdx.y == 1 ? k : v);
    unsigned short* dst = blockIdx.y == 0 ? qb : (blockIdx.y == 1 ? kb : vb);
    floatv4 x = ((const floatv4*)src)[i];
    ushortv4 o;
    o.x = f2bf(x.x); o.y = f2bf(x.y); o.z = f2bf(x.z); o.w = f2bf(x.w);
    ((ushortv4*)dst)[i] = o;
}

// ---------------- weight transpose + convert (4 weights merged) ----------------
__global__ __launch_bounds__(256) void wtrans4(
    const float* __restrict__ W0, const float* __restrict__ W1,
    const float* __restrict__ W2, const float* __restrict__ W3,
    unsigned short* __restrict__ T0, unsigned short* __restrict__ T1,
    unsigned short* __restrict__ T2, unsigned short* __restrict__ T3) {
    int sel = blockIdx.z;
    const float* W = sel == 0 ? W0 : (sel == 1 ? W1 : (sel == 2 ? W2 : W3));
    unsigned short* Wt = sel == 0 ? T0 : (sel == 1 ? T1 : (sel == 2 ? T2 : T3));
    __shared__ float tile[32][33];
    int tx = threadIdx.x & 31, ty = threadIdx.x >> 5;
    int nb = blockIdx.x * 32, kb = blockIdx.y * 32;
#pragma unroll
    for (int i = 0; i < 4; i++)
        tile[ty + i * 8][tx] = W[(size_t)(kb + ty + i * 8) * DMODEL + nb + tx];
    __syncthreads();
#pragma unroll
    for (int i = 0; i < 4; i++)
        Wt[(size_t)(nb + ty + i * 8) * DMODEL + kb + tx] = f2bf(tile[tx][ty + i * 8]);
}

// ---------------- GEMM core: 128x128 tile, BK=64, 4 waves, swizzled LDS ----------------
__device__ __forceinline__ void stage_tile_sw(const unsigned short* __restrict__ src, int ld,
                                              unsigned short* lds) {
    int t = threadIdx.x;
#pragma unroll
    for (int i = 0; i < 4; i++) {
        int pos = i * 256 + t;            // 16B granule index
        int row = pos >> 3;
        int g = pos & 7;
        int kcol = (g ^ (row & 7)) * 8;   // inverse-swizzled source column
        __builtin_amdgcn_global_load_lds(
            (__attribute__((address_space(1))) void*)(src + row * ld + kcol),
            (__attribute__((address_space(3))) void*)(lds + pos * 8), 16, 0, 0);
    }
}

__device__ __forceinline__ bf16x8 frag_ld(const unsigned short* lds, int row, int koff) {
    int idx = row * 64 + (koff ^ ((row & 7) << 3));
    return *(const bf16x8*)(lds + idx);
}

__device__ __forceinline__ void gemm_core(const unsigned short* __restrict__ A,
                                          const unsigned short* __restrict__ Bt,
                                          int mbase, int nbase,
                                          unsigned short* As, unsigned short* Bs,
                                          f32x4 acc[4][4]) {
    int tid = threadIdx.x;
    int w = tid >> 6, lane = tid & 63, lg = lane >> 4, li = lane & 15;
    int wm = w >> 1, wn = w & 1;
#pragma unroll
    for (int mi = 0; mi < 4; mi++)
#pragma unroll
        for (int ni = 0; ni < 4; ni++) acc[mi][ni] = f32x4{0.f, 0.f, 0.f, 0.f};

    for (int ks = 0; ks < DMODEL / 64; ks++) {
        __syncthreads();
        stage_tile_sw(A + (size_t)mbase * DMODEL + ks * 64, DMODEL, As);
        stage_tile_sw(Bt + (size_t)nbase * DMODEL + ks * 64, DMODEL, Bs);
        __syncthreads();
        bf16x8 af[2][4], bfr[2][4];
#pragma unroll
        for (int kc = 0; kc < 2; kc++) {
#pragma unroll
            for (int mi = 0; mi < 4; mi++)
                af[kc][mi] = frag_ld(As, wm * 64 + mi * 16 + li, kc * 32 + lg * 8);
#pragma unroll
            for (int ni = 0; ni < 4; ni++)
                bfr[kc][ni] = frag_ld(Bs, wn * 64 + ni * 16 + li, kc * 32 + lg * 8);
        }
#pragma unroll
        for (int kc = 0; kc < 2; kc++)
#pragma unroll
            for (int mi = 0; mi < 4; mi++)
#pragma unroll
                for (int ni = 0; ni < 4; ni++)
                    acc[mi][ni] = MFMA16(af[kc][mi], bfr[kc][ni], acc[mi][ni]);
    }
}

// ---------------- fused QKV projection ----------------
// seg 0/1 -> Qp/Kp [B,H,S,64]; seg 2 -> Vt [B,H,64,S] (transposed, packed 8B stores)
__global__ __launch_bounds__(256) void gemm_qkv(
    const unsigned short* __restrict__ qb, const unsigned short* __restrict__ kbuf,
    const unsigned short* __restrict__ vb,
    const unsigned short* __restrict__ Wqt, const unsigned short* __restrict__ Wkt,
    const unsigned short* __restrict__ Wvt,
    unsigned short* __restrict__ Qp, unsigned short* __restrict__ Kp,
    unsigned short* __restrict__ Vt) {
    __shared__ unsigned short As[128 * 64], Bs[128 * 64];
    int nt = blockIdx.x;
    int seg = nt >> 3;
    int nbase = (nt & 7) * 128;
    int mbase = blockIdx.y * 128;
    const unsigned short* A = seg == 0 ? qb : (seg == 1 ? kbuf : vb);
    const unsigned short* Bt = seg == 0 ? Wqt : (seg == 1 ? Wkt : Wvt);

    f32x4 acc[4][4];
    gemm_core(A, Bt, mbase, nbase, As, Bs, acc);

    int tid = threadIdx.x, w = tid >> 6, lane = tid & 63, lg = lane >> 4, li = lane & 15;
    int wm = w >> 1, wn = w & 1;
    if (seg == 2) {
#pragma unroll
        for (int mi = 0; mi < 4; mi++)
#pragma unroll
            for (int ni = 0; ni < 4; ni++) {
                int n = nbase + wn * 64 + ni * 16 + li;
                int h = n >> 6, d = n & 63;
                int m0 = mbase + wm * 64 + mi * 16 + lg * 4;
                int b = m0 >> 11, sI = m0 & 2047;
                ushortv4 pk;
#pragma unroll
                for (int r = 0; r < 4; r++) pk[r] = f2bf(acc[mi][ni][r]);
                *(ushortv4*)(Vt + (((size_t)((b * NHEAD + h) * 64 + d)) << 11) + sI) = pk;
            }
    } else {
        unsigned short* Out = seg == 0 ? Qp : Kp;
#pragma unroll
        for (int mi = 0; mi < 4; mi++)
#pragma unroll
            for (int ni = 0; ni < 4; ni++) {
                int n = nbase + wn * 64 + ni * 16 + li;
                int h = n >> 6, d = n & 63;
#pragma unroll
                for (int r = 0; r < 4; r++) {
                    int m = mbase + wm * 64 + mi * 16 + lg * 4 + r;
                    int b = m >> 11, sI = m & 2047;
                    Out[(size_t)((b * NHEAD + h) * SS + sI) * 64 + d] = f2bf(acc[mi][ni][r]);
                }
            }
    }
}

// ---------------- output projection + bias + residual ----------------
__global__ __launch_bounds__(256) void gemm_out(
    const unsigned short* __restrict__ Ob, const unsigned short* __restrict__ Wot,
    const float* __restrict__ bo, const float* __restrict__ qres, float* __restrict__ Y) {
    __shared__ unsigned short As[128 * 64], Bs[128 * 64];
    int nbase = blockIdx.x * 128;
    int mbase = blockIdx.y * 128;

    f32x4 acc[4][4];
    gemm_core(Ob, Wot, mbase, nbase, As, Bs, acc);

    int tid = threadIdx.x, w = tid >> 6, lane = tid & 63, lg = lane >> 4, li = lane & 15;
    int wm = w >> 1, wn = w & 1;
#pragma unroll
    for (int mi = 0; mi < 4; mi++)
#pragma unroll
        for (int ni = 0; ni < 4; ni++) {
            int n = nbase + wn * 64 + ni * 16 + li;
            float bov = bo[n];
#pragma unroll
            for (int r = 0; r < 4; r++) {
                int m = mbase + wm * 64 + mi * 16 + lg * 4 + r;
                size_t idx = (size_t)m * DMODEL + n;
                Y[idx] = acc[mi][ni][r] + bov + qres[idx];
            }
        }
}

// ---------------- fused attention (swapped-score layout) ----------------
// grid (16, 32): x = q-block (128 rows), y = bh. 4 waves, 32 q-rows/wave.
// Scores computed as S^T = mfma(K_frag, Q_frag): lane holds q = fq*16+li (fixed),
// k = k0 + fk*16 + lg*4 + r  -> float4 P stores, b64 LDS writes, cheap reduce.
__device__ __forceinline__ void stage_vt(const unsigned short* __restrict__ src, int s0,
                                         unsigned short* lds, int tid) {
#pragma unroll
    for (int i = 0; i < 4; i++) {
        int pos = i * 256 + tid;          // granule (16B) index, 1024 total = 64x128 u16
        int row = pos >> 4;               // d row
        int P = pos & 15;
        int scol = s0 + ((P ^ (row & 7)) << 3);  // inverse-swizzled source col
        __builtin_amdgcn_global_load_lds(
            (__attribute__((address_space(1))) void*)(src + (size_t)row * SS + scol),
            (__attribute__((address_space(3))) void*)(lds + pos * 8), 16, 0, 0);
    }
}

__global__ __launch_bounds__(256) void attn_fused(
    const unsigned short* __restrict__ Qp, const unsigned short* __restrict__ Kp,
    const unsigned short* __restrict__ Vt, const int* __restrict__ mask,
    float* __restrict__ attn_out, unsigned short* __restrict__ Ob) {
    __shared__ unsigned short Plds[4 * 32 * 128];  // per-wave 32x128 bf16, swizzled
    __shared__ unsigned short Vs[2][64 * 128];     // V^T tile [d][s], swizzled, dbuf

    int bh = blockIdx.y;
    int b = bh >> 4;
    int q0 = blockIdx.x * 128;
    int tid = threadIdx.x, w = tid >> 6, lane = tid & 63, lg = lane >> 4, li = lane & 15;
    const unsigned short* Qb = Qp + (size_t)bh * SS * 64;
    const unsigned short* Kb = Kp + (size_t)bh * SS * 64;
    const unsigned short* Vtb = Vt + (size_t)bh * 64 * SS;
    const int* mb = mask + b * SS;
    int qw = q0 + w * 32;

    // prefetch V^T tile 0 (lands during pass A)
    stage_vt(Vtb, 0, &Vs[0][0], tid);

    // Q fragments (also serve as MFMA B-operand: identical layout)
    bf16x8 qa[2][2];
#pragma unroll
    for (int fq = 0; fq < 2; fq++)
#pragma unroll
        for (int dc = 0; dc < 2; dc++) {
            int q = qw + fq * 16 + li;
            qa[fq][dc] = *(const bf16x8*)(Qb + (size_t)q * 64 + dc * 32 + lg * 8);
        }

    float mrun[2] = {-3.0e38f, -3.0e38f}, lrun[2] = {0.f, 0.f};

    // ---- pass A: online max/sum (no barriers, per-wave independent) ----
    for (int kt = 0; kt < SS / 128; kt++) {
        int k0 = kt * 128;
        float s[2][8][4];
#pragma unroll
        for (int fk = 0; fk < 8; fk++) {
            int kcol = k0 + fk * 16 + li;
            bf16x8 kf0 = *(const bf16x8*)(Kb + (size_t)kcol * 64 + lg * 8);
            bf16x8 kf1 = *(const bf16x8*)(Kb + (size_t)kcol * 64 + 32 + lg * 8);
            intv4 m4 = *(const intv4*)(mb + k0 + fk * 16 + lg * 4);
#pragma unroll
            for (int fq = 0; fq < 2; fq++) {
                f32x4 sc = f32x4{0.f, 0.f, 0.f, 0.f};
                sc = MFMA16(kf0, qa[fq][0], sc);
                sc = MFMA16(kf1, qa[fq][1], sc);
#pragma unroll
                for (int r = 0; r < 4; r++)
                    s[fq][fk][r] = (m4[r] == 0) ? NEGV : sc[r] * 0.03125f;
            }
        }
#pragma unroll
        for (int fq = 0; fq < 2; fq++) {
            float tm = s[fq][0][0];
#pragma unroll
            for (int fk = 0; fk < 8; fk++)
#pragma unroll
                for (int r = 0; r < 4; r++) tm = fmaxf(tm, s[fq][fk][r]);
            tm = fmaxf(tm, __shfl_xor(tm, 16));
            tm = fmaxf(tm, __shfl_xor(tm, 32));
            float mnew = fmaxf(mrun[fq], tm);
            float corr = __expf(mrun[fq] - mnew);
            float ps = 0.f;
#pragma unroll
            for (int fk = 0; fk < 8; fk++)
#pragma unroll
                for (int r = 0; r < 4; r++) ps += __expf(s[fq][fk][r] - mnew);
            ps += __shfl_xor(ps, 16);
            ps += __shfl_xor(ps, 32);
            lrun[fq] = lrun[fq] * corr + ps;
            mrun[fq] = mnew;
        }
    }
    float linv[2] = {1.0f / lrun[0], 1.0f / lrun[1]};

    // ---- pass B: normalized P write (global f32 + LDS bf16) + PV ----
    f32x4 oacc[2][4];
#pragma unroll
    for (int fq = 0; fq < 2; fq++)
#pragma unroll
        for (int gd = 0; gd < 4; gd++) oacc[fq][gd] = f32x4{0.f, 0.f, 0.f, 0.f};

    unsigned short* Pw = Plds + w * (32 * 128);
    float* arow0 = attn_out + ((size_t)bh * SS + qw + li) * SS + lg * 4;
    float* arow1 = arow0 + (size_t)16 * SS;

    for (int kt = 0; kt < SS / 128; kt++) {
        int k0 = kt * 128;
#pragma unroll
        for (int fk = 0; fk < 8; fk++) {
            int kcol = k0 + fk * 16 + li;
            bf16x8 kf0 = *(const bf16x8*)(Kb + (size_t)kcol * 64 + lg * 8);
            bf16x8 kf1 = *(const bf16x8*)(Kb + (size_t)kcol * 64 + 32 + lg * 8);
            intv4 m4 = *(const intv4*)(mb + k0 + fk * 16 + lg * 4);
#pragma unroll
            for (int fq = 0; fq < 2; fq++) {
                f32x4 sc = f32x4{0.f, 0.f, 0.f, 0.f};
                sc = MFMA16(kf0, qa[fq][0], sc);
                sc = MFMA16(kf1, qa[fq][1], sc);
                floatv4 pv;
#pragma unroll
                for (int r = 0; r < 4; r++) {
                    float sv = (m4[r] == 0) ? NEGV : sc[r] * 0.03125f;
                    pv[r] = __expf(sv - mrun[fq]) * linv[fq];
                }
                *(floatv4*)((fq == 0 ? arow0 : arow1) + k0 + fk * 16) = pv;
                ushortv4 pk;
#pragma unroll
                for (int r = 0; r < 4; r++) pk[r] = f2bf(pv[r]);
                int qr = fq * 16 + li;
                int c = (fk * 16 + lg * 4) ^ ((qr & 7) << 3);
                *(ushortv4*)(Pw + qr * 128 + c) = pk;
            }
        }
        // prefetch next V^T tile into other buffer; counted wait for current
        if (kt + 1 < SS / 128) {
            stage_vt(Vtb, k0 + 128, &Vs[(kt + 1) & 1][0], tid);
            asm volatile("s_waitcnt vmcnt(20)" ::: "memory");
        } else {
            asm volatile("s_waitcnt vmcnt(16)" ::: "memory");
        }
        __builtin_amdgcn_sched_barrier(0);
        __builtin_amdgcn_s_barrier();
        __builtin_amdgcn_sched_barrier(0);

        const unsigned short* Vc = &Vs[kt & 1][0];
#pragma unroll
        for (int kc = 0; kc < 4; kc++) {
            bf16x8 pa[2];
#pragma unroll
            for (int fq = 0; fq < 2; fq++) {
                int qr = fq * 16 + li;
                pa[fq] = *(const bf16x8*)(Pw + qr * 128 + ((kc * 32 + lg * 8) ^ ((qr & 7) << 3)));
            }
            bf16x8 vf[4];
#pragma unroll
            for (int gd = 0; gd < 4; gd++) {
                int rr = gd * 16 + li;
                vf[gd] = *(const bf16x8*)(Vc + rr * 128 + ((kc * 32 + lg * 8) ^ ((rr & 7) << 3)));
            }
#pragma unroll
            for (int fq = 0; fq < 2; fq++)
#pragma unroll
                for (int gd = 0; gd < 4; gd++)
                    oacc[fq][gd] = MFMA16(pa[fq], vf[gd], oacc[fq][gd]);
        }
        __builtin_amdgcn_sched_barrier(0);
        __builtin_amdgcn_s_barrier();  // separate PV(t) reads from stage(t+2) writes
    }

    // epilogue: O -> [b*S + s][h*64 + d] bf16 (rows = q, cols = d)
    int h = bh & 15;
#pragma unroll
    for (int fq = 0; fq < 2; fq++)
#pragma unroll
        for (int gd = 0; gd < 4; gd++)
#pragma unroll
            for (int r = 0; r < 4; r++) {
                int srow = qw + fq * 16 + lg * 4 + r;
                int d = gd * 16 + li;
                Ob[(size_t)(b * SS + srow) * DMODEL + h * 64 + d] = f2bf(oacc[fq][gd][r]);
            }
}

// ---------------- LayerNorm ----------------
__global__ __launch_bounds__(256) void ln_kernel(const float* __restrict__ Y,
                                                 const float* __restrict__ gamma,
                                                 const float* __restrict__ beta,
                                                 float* __restrict__ out) {
    int row = blockIdx.x;
    int t = threadIdx.x;
    floatv4 v = ((const floatv4*)(Y + (size_t)row * DMODEL))[t];
    float s1 = v.x + v.y + v.z + v.w;
    float s2 = v.x * v.x + v.y * v.y + v.z * v.z + v.w * v.w;
#pragma unroll
    for (int m = 1; m < 64; m <<= 1) { s1 += __shfl_xor(s1, m); s2 += __shfl_xor(s2, m); }
    __shared__ float red[8];
    int w = t >> 6, lane = t & 63;
    if (lane == 0) { red[w] = s1; red[4 + w] = s2; }
    __syncthreads();
    s1 = red[0] + red[1] + red[2] + red[3];
    s2 = red[4] + red[5] + red[6] + red[7];
    float mu = s1 * (1.0f / DMODEL);
    float var = s2 * (1.0f / DMODEL) - mu * mu;
    float rstd = rsqrtf(var + 1e-5f);
    floatv4 g = ((const floatv4*)gamma)[t];
    floatv4 bb = ((const floatv4*)beta)[t];
    floatv4 o;
    o.x = (v.x - mu) * rstd * g.x + bb.x;
    o.y = (v.y - mu) * rstd * g.y + bb.y;
    o.z = (v.z - mu) * rstd * g.z + bb.z;
    o.w = (v.w - mu) * rstd * g.w + bb.w;
    ((floatv4*)(out + (size_t)row * DMODEL))[t] = o;
}

// ---------------- launch ----------------
extern "C" void kernel_launch(void* const* d_in, const int* in_sizes, int n_in,
                              void* d_out, int out_size, void* d_ws, size_t ws_size,
                              hipStream_t stream) {
    const float* q = (const float*)d_in[0];
    const float* k = (const float*)d_in[1];
    const float* v = (const float*)d_in[2];
    const int* mask = (const int*)d_in[3];
    const float* Wq = (const float*)d_in[4];
    const float* Wk = (const float*)d_in[5];
    const float* Wv = (const float*)d_in[6];
    const float* Wo = (const float*)d_in[7];
    const float* bo = (const float*)d_in[8];
    const float* gamma = (const float*)d_in[9];
    const float* beta = (const float*)d_in[10];

    float* out = (float*)d_out;
    float* attn = out + (size_t)BB * SS * DMODEL;

    const size_t NTOK = (size_t)BB * SS;          // 4096
    unsigned short* qb = (unsigned short*)d_ws;   // [4096][1024] bf16
    unsigned short* kb = qb + NTOK * DMODEL;
    unsigned short* vb = kb + NTOK * DMODEL;
    unsigned short* Wqt = vb + NTOK * DMODEL;     // [1024][1024] bf16 (transposed)
    unsigned short* Wkt = Wqt + (size_t)DMODEL * DMODEL;
    unsigned short* Wvt = Wkt + (size_t)DMODEL * DMODEL;
    unsigned short* Wot = Wvt + (size_t)DMODEL * DMODEL;
    unsigned short* Qp = Wot + (size_t)DMODEL * DMODEL;  // [B,H,S,64] bf16
    unsigned short* Kp = Qp + NTOK * DMODEL;
    unsigned short* Vt = Kp + NTOK * DMODEL;      // [B,H,64,S] bf16 (transposed)
    unsigned short* Ob = Vt + NTOK * DMODEL;      // [4096][1024] bf16
    float* Y = (float*)qb;                        // reuse qb+kb region post-attention

    const int n4 = (int)(NTOK * DMODEL / 4);
    cvt3<<<dim3(n4 / 256, 3), 256, 0, stream>>>(q, k, v, qb, kb, vb, n4);
    wtrans4<<<dim3(32, 32, 4), 256, 0, stream>>>(Wq, Wk, Wv, Wo, Wqt, Wkt, Wvt, Wot);

    gemm_qkv<<<dim3(24, 32), 256, 0, stream>>>(qb, kb, vb, Wqt, Wkt, Wvt, Qp, Kp, Vt);

    attn_fused<<<dim3(16, 32), 256, 0, stream>>>(Qp, Kp, Vt, mask, attn, Ob);

    gemm_out<<<dim3(8, 32), 256, 0, stream>>>(Ob, Wot, bo, q, Y);

    ln_kernel<<<(int)NTOK, 256, 0, stream>>>(Y, gamma, beta, out);
}